// Round 2
// baseline (130.840 us; speedup 1.0000x reference)
//
#include <hip/hip_runtime.h>

#define NC 20
#define THREADS 256
#define BLOCKS 2048
#define EPSF 1e-10f
#define NPK 30   // 10 packed class-pairs x 3 histograms (classes 1..19 only)

// Count classes 1..19 (class 0 is dropped by mean(dscs[1:]) in the reference).
// Per-lane register counters, fully unrolled class loop -> pure VALU, no LDS
// in the hot loop. Each thread handles exactly 32 element-pairs, so every
// per-thread count <= 32; block sums <= 256*32 = 8192 -> 16-bit packing safe.
__global__ __launch_bounds__(THREADS) void dice_count(
    const int* __restrict__ pred, const int* __restrict__ tgt,
    unsigned int* __restrict__ gcounts, int n4_total)
{
    __shared__ unsigned int sdata[THREADS * NPK];

    unsigned cp[21], ct[21], ctp[21];   // index 20 stays 0 (pad for packing)
    #pragma unroll
    for (int c = 0; c < 21; ++c) { cp[c] = 0u; ct[c] = 0u; ctp[c] = 0u; }

    const int tid = threadIdx.x;
    const long long gt  = (long long)blockIdx.x * THREADS + tid;
    const long long nTh = (long long)BLOCKS * THREADS;
    const int4* p4 = (const int4*)pred;
    const int4* t4 = (const int4*)tgt;

    for (long long i = gt; i < n4_total; i += nTh) {
        int4 p = p4[i];
        int4 t = t4[i];
        #define COUNT_ONE(pv, tv)                                              \
            {                                                                  \
                const int _p = (pv), _t = (tv);                                \
                const bool _e = (_p == _t);                                    \
                _Pragma("unroll")                                              \
                for (int c = 1; c < NC; ++c) {                                 \
                    const bool _mp = (_p == c);                                \
                    cp[c]  += _mp;                                             \
                    ct[c]  += (_t == c);                                       \
                    ctp[c] += (_mp && _e);                                     \
                }                                                              \
            }
        COUNT_ONE(p.x, t.x)
        COUNT_ONE(p.y, t.y)
        COUNT_ONE(p.z, t.z)
        COUNT_ONE(p.w, t.w)
        #undef COUNT_ONE
    }

    // Pack two 16-bit class counters per u32: (2k+1, 2k+2), k=0..9.
    #pragma unroll
    for (int k = 0; k < 10; ++k) {
        sdata[tid * NPK + k]      = cp [2 * k + 1] | (cp [2 * k + 2] << 16);
        sdata[tid * NPK + 10 + k] = ct [2 * k + 1] | (ct [2 * k + 2] << 16);
        sdata[tid * NPK + 20 + k] = ctp[2 * k + 1] | (ctp[2 * k + 2] << 16);
    }
    __syncthreads();

    // Column reduce: 8 partials per column, 30 columns -> 240 threads.
    if (tid < 8 * NPK) {
        const int j   = tid >> 3;   // column 0..29
        const int sub = tid & 7;    // partial 0..7, 32 rows each
        unsigned s = 0;
        const int r0 = sub * 32;
        #pragma unroll
        for (int r = 0; r < 32; ++r) s += sdata[(r0 + r) * NPK + j];
        #pragma unroll
        for (int d = 4; d >= 1; d >>= 1) s += __shfl_down(s, d, 8);
        if (sub == 0) {
            const int h  = j / 10;          // histogram 0..2
            const int k  = j % 10;
            const int c1 = 2 * k + 1;       // class 1..19
            atomicAdd(&gcounts[h * NC + c1], s & 0xFFFFu);
            if (c1 + 1 < NC) atomicAdd(&gcounts[h * NC + c1 + 1], s >> 16);
        }
    }
}

__global__ void dice_final(const unsigned int* __restrict__ gcounts,
                           float* __restrict__ out)
{
    const int c = threadIdx.x;  // 64 lanes, classes 1..19 contribute
    float contrib = 0.0f;
    if (c >= 1 && c < NC) {
        float tp = (float)gcounts[2 * NC + c];
        float pc = (float)gcounts[c];
        float tc = (float)gcounts[NC + c];
        contrib = 2.0f * tp / (pc + tc + EPSF);
    }
    #pragma unroll
    for (int d = 32; d >= 1; d >>= 1) contrib += __shfl_down(contrib, d, 64);
    if (c == 0) out[0] = contrib * (1.0f / 19.0f);
}

extern "C" void kernel_launch(void* const* d_in, const int* in_sizes, int n_in,
                              void* d_out, int out_size, void* d_ws, size_t ws_size,
                              hipStream_t stream) {
    const int* pred = (const int*)d_in[0];
    const int* tgt  = (const int*)d_in[1];
    unsigned int* gcounts = (unsigned int*)d_ws;

    // d_ws is NOT re-poisoned between replays -> zero the 60 counters each call.
    hipMemsetAsync(d_ws, 0, 3 * NC * sizeof(unsigned int), stream);

    const int n  = in_sizes[0];        // 16,777,216 (divisible by 4)
    const int n4 = n >> 2;

    dice_count<<<BLOCKS, THREADS, 0, stream>>>(pred, tgt, gcounts, n4);
    dice_final<<<1, 64, 0, stream>>>(gcounts, (float*)d_out);
}

// Round 3
// 64.442 us; speedup vs baseline: 2.0303x; 2.0303x over previous
//
#include <hip/hip_runtime.h>

#define NC 20
#define NB (NC * NC)       // 400 joint (pred,tgt) bins
#define THREADS 256
#define BLOCKS 2048
#define UN 4               // int4s per thread per main-loop iteration
#define EPSF 1e-10f

// Joint histogram: h[p*20+t]. pred_cnt = row sums, tgt_cnt = col sums,
// tp = diagonal. One LDS atomic + ~3 VALU per element pair.
__global__ __launch_bounds__(THREADS) void dice_joint(
    const int* __restrict__ pred, const int* __restrict__ tgt,
    unsigned int* __restrict__ gcounts, long long n4)
{
    __shared__ unsigned int h[4 * NB];   // one 400-bin copy per wave
    const int tid = threadIdx.x;

    for (int k = tid; k < 4 * NB; k += THREADS) h[k] = 0u;
    __syncthreads();

    unsigned int* hw = &h[(tid >> 6) * NB];
    const int4* p4 = (const int4*)pred;
    const int4* t4 = (const int4*)tgt;
    const long long stride = (long long)BLOCKS * THREADS;
    long long i = (long long)blockIdx.x * THREADS + tid;

    // Main loop: hoist all 2*UN loads ahead of the atomics so the compiler
    // can overlap load latency with the previous group's LDS work.
    for (; i + (UN - 1) * stride < n4; i += UN * stride) {
        int4 P[UN], T[UN];
        #pragma unroll
        for (int k = 0; k < UN; ++k) P[k] = p4[i + k * stride];
        #pragma unroll
        for (int k = 0; k < UN; ++k) T[k] = t4[i + k * stride];
        #pragma unroll
        for (int k = 0; k < UN; ++k) {
            atomicAdd(&hw[P[k].x * NC + T[k].x], 1u);
            atomicAdd(&hw[P[k].y * NC + T[k].y], 1u);
            atomicAdd(&hw[P[k].z * NC + T[k].z], 1u);
            atomicAdd(&hw[P[k].w * NC + T[k].w], 1u);
        }
    }
    // Generic tail (empty for the benchmark shape).
    for (; i < n4; i += stride) {
        int4 P = p4[i];
        int4 T = t4[i];
        atomicAdd(&hw[P.x * NC + T.x], 1u);
        atomicAdd(&hw[P.y * NC + T.y], 1u);
        atomicAdd(&hw[P.z * NC + T.z], 1u);
        atomicAdd(&hw[P.w * NC + T.w], 1u);
    }
    __syncthreads();

    // Fold the 4 per-wave copies into copy 0.
    for (int k = tid; k < NB; k += THREADS)
        h[k] = h[k] + h[NB + k] + h[2 * NB + k] + h[3 * NB + k];
    __syncthreads();

    // 57 class sums (3 histograms x classes 1..19) -> global atomics.
    if (tid < 3 * (NC - 1)) {
        const int which = tid / (NC - 1);       // 0: pred, 1: tgt, 2: tp
        const int c     = tid % (NC - 1) + 1;   // class 1..19
        unsigned s = 0;
        if (which == 0) {
            #pragma unroll
            for (int t = 0; t < NC; ++t) s += h[c * NC + t];
        } else if (which == 1) {
            #pragma unroll
            for (int p = 0; p < NC; ++p) s += h[p * NC + c];
        } else {
            s = h[c * NC + c];
        }
        atomicAdd(&gcounts[which * NC + c], s);
    }
}

__global__ void dice_final(const unsigned int* __restrict__ gcounts,
                           float* __restrict__ out)
{
    const int c = threadIdx.x;  // 64 lanes, classes 1..19 contribute
    float contrib = 0.0f;
    if (c >= 1 && c < NC) {
        float tp = (float)gcounts[2 * NC + c];
        float pc = (float)gcounts[c];
        float tc = (float)gcounts[NC + c];
        contrib = 2.0f * tp / (pc + tc + EPSF);
    }
    #pragma unroll
    for (int d = 32; d >= 1; d >>= 1) contrib += __shfl_down(contrib, d, 64);
    if (c == 0) out[0] = contrib * (1.0f / 19.0f);
}

extern "C" void kernel_launch(void* const* d_in, const int* in_sizes, int n_in,
                              void* d_out, int out_size, void* d_ws, size_t ws_size,
                              hipStream_t stream) {
    const int* pred = (const int*)d_in[0];
    const int* tgt  = (const int*)d_in[1];
    unsigned int* gcounts = (unsigned int*)d_ws;

    // d_ws is NOT re-poisoned between replays -> zero the 60 counters each call.
    hipMemsetAsync(d_ws, 0, 3 * NC * sizeof(unsigned int), stream);

    const long long n  = in_sizes[0];   // 16,777,216 (divisible by 4)
    const long long n4 = n >> 2;

    dice_joint<<<BLOCKS, THREADS, 0, stream>>>(pred, tgt, gcounts, n4);
    dice_final<<<1, 64, 0, stream>>>(gcounts, (float*)d_out);
}

// Round 4
// 64.421 us; speedup vs baseline: 2.0310x; 1.0003x over previous
//
#include <hip/hip_runtime.h>

#define NC 20
#define NB (NC * NC)       // 400 joint (pred,tgt) bins
#define THREADS 256
#define BLOCKS 2048
#define UN 8               // int4s per thread: 2048*256*8 = 4,194,304 = n/4 exactly
#define EPSF 1e-10f

// Joint histogram h[p*20+t]: pred_cnt = row sums, tgt_cnt = col sums,
// tp = diagonal. One LDS atomic + ~3 VALU per element pair.
// All 16 loads per thread issued as ONE burst -> single exposed-latency round.
__global__ __launch_bounds__(THREADS) void dice_joint(
    const int* __restrict__ pred, const int* __restrict__ tgt,
    unsigned int* __restrict__ gcounts, int n4)
{
    __shared__ unsigned int h[4 * NB];   // one 400-bin copy per wave
    const int tid = threadIdx.x;

    for (int k = tid; k < 4 * NB; k += THREADS) h[k] = 0u;
    __syncthreads();

    unsigned int* hw = &h[(tid >> 6) * NB];
    const int4* p4 = (const int4*)pred;
    const int4* t4 = (const int4*)tgt;
    const int stride = BLOCKS * THREADS;
    int i = blockIdx.x * THREADS + tid;

    if (i + (UN - 1) * stride < n4) {
        // Full burst: 16 independent int4 loads in flight per thread.
        int4 P[UN], T[UN];
        #pragma unroll
        for (int k = 0; k < UN; ++k) P[k] = p4[i + k * stride];
        #pragma unroll
        for (int k = 0; k < UN; ++k) T[k] = t4[i + k * stride];
        #pragma unroll
        for (int k = 0; k < UN; ++k) {
            atomicAdd(&hw[P[k].x * NC + T[k].x], 1u);
            atomicAdd(&hw[P[k].y * NC + T[k].y], 1u);
            atomicAdd(&hw[P[k].z * NC + T[k].z], 1u);
            atomicAdd(&hw[P[k].w * NC + T[k].w], 1u);
        }
    } else {
        // Generic fallback (unused at the benchmark shape).
        for (; i < n4; i += stride) {
            int4 P = p4[i];
            int4 T = t4[i];
            atomicAdd(&hw[P.x * NC + T.x], 1u);
            atomicAdd(&hw[P.y * NC + T.y], 1u);
            atomicAdd(&hw[P.z * NC + T.z], 1u);
            atomicAdd(&hw[P.w * NC + T.w], 1u);
        }
    }
    __syncthreads();

    // Fold the 4 per-wave copies into copy 0.
    for (int k = tid; k < NB; k += THREADS)
        h[k] = h[k] + h[NB + k] + h[2 * NB + k] + h[3 * NB + k];
    __syncthreads();

    // 57 class sums (3 histograms x classes 1..19) -> global atomics.
    if (tid < 3 * (NC - 1)) {
        const int which = tid / (NC - 1);       // 0: pred, 1: tgt, 2: tp
        const int c     = tid % (NC - 1) + 1;   // class 1..19
        unsigned s = 0;
        if (which == 0) {
            #pragma unroll
            for (int t = 0; t < NC; ++t) s += h[c * NC + t];
        } else if (which == 1) {
            #pragma unroll
            for (int p = 0; p < NC; ++p) s += h[p * NC + c];
        } else {
            s = h[c * NC + c];
        }
        atomicAdd(&gcounts[which * NC + c], s);
    }
}

__global__ void dice_final(const unsigned int* __restrict__ gcounts,
                           float* __restrict__ out)
{
    const int c = threadIdx.x;  // 64 lanes, classes 1..19 contribute
    float contrib = 0.0f;
    if (c >= 1 && c < NC) {
        float tp = (float)gcounts[2 * NC + c];
        float pc = (float)gcounts[c];
        float tc = (float)gcounts[NC + c];
        contrib = 2.0f * tp / (pc + tc + EPSF);
    }
    #pragma unroll
    for (int d = 32; d >= 1; d >>= 1) contrib += __shfl_down(contrib, d, 64);
    if (c == 0) out[0] = contrib * (1.0f / 19.0f);
}

extern "C" void kernel_launch(void* const* d_in, const int* in_sizes, int n_in,
                              void* d_out, int out_size, void* d_ws, size_t ws_size,
                              hipStream_t stream) {
    const int* pred = (const int*)d_in[0];
    const int* tgt  = (const int*)d_in[1];
    unsigned int* gcounts = (unsigned int*)d_ws;

    // d_ws is NOT re-poisoned between replays -> zero the 60 counters each call.
    hipMemsetAsync(d_ws, 0, 3 * NC * sizeof(unsigned int), stream);

    const int n  = in_sizes[0];        // 16,777,216 (divisible by 4)
    const int n4 = n >> 2;

    dice_joint<<<BLOCKS, THREADS, 0, stream>>>(pred, tgt, gcounts, n4);
    dice_final<<<1, 64, 0, stream>>>(gcounts, (float*)d_out);
}

// Round 5
// 61.373 us; speedup vs baseline: 2.1319x; 1.0497x over previous
//
#include <hip/hip_runtime.h>

#define NC 20
#define THREADS 256
#define BLOCKS 1024
#define GRAN 16            // int4 granules/thread: 1024*256*16 = 4,194,304 = n/4 exactly
#define EPSF 1e-10f

typedef unsigned long long u64;
typedef unsigned int u32;

// One-hot (3-bit fields, 20 classes in 60 bits) accumulate for one pair.
static __device__ __forceinline__ void pair_update(int p, int t,
                                                   u64& np, u64& nt, u64& ne)
{
    u64 ip = 1ull << (3 * p);
    u64 it = 1ull << (3 * t);
    np += ip;
    nt += it;
    ne += (p == t) ? ip : 0ull;   // cndmask, branchless
}

// Bit-sliced histogram: no LDS in the hot loop, pure VALU counting.
__global__ __launch_bounds__(THREADS) void dice_slice(
    const int* __restrict__ pred, const int* __restrict__ tgt,
    u32* __restrict__ gcounts, int n4)
{
    constexpr u64 M = 0x01C71C71C71C71C7ull;  // 3-bit mask at 6-bit spacing (10 slots)
    __shared__ u32 sdata[THREADS * 31 + 256]; // 30 packed cols + pad, + partial area
    const int tid = threadIdx.x;
    const int S   = BLOCKS * THREADS;
    const int g   = blockIdx.x * THREADS + tid;
    const int4* p4 = (const int4*)pred;
    const int4* t4 = (const int4*)tgt;

    // 6-bit-spaced accumulators; even classes in *e*, odd in *o*.
    // Two banks so no 6-bit field exceeds 32 (8 granules x 4 pairs).
    u64 aeP=0, aoP=0, aeT=0, aoT=0, aeE=0, aoE=0;   // granules 0..7
    u64 beP=0, boP=0, beT=0, boT=0, beE=0, boE=0;   // granules 8..15

    #pragma unroll
    for (int k = 0; k < GRAN; ++k) {
        const int idx = g + k * S;
        int4 P = make_int4(0,0,0,0), T = make_int4(0,0,0,0);
        if (idx < n4) { P = p4[idx]; T = t4[idx]; }   // OOB -> class 0 (ignored)
        u64 np = 0, nt = 0, ne = 0;
        pair_update(P.x, T.x, np, nt, ne);
        pair_update(P.y, T.y, np, nt, ne);
        pair_update(P.z, T.z, np, nt, ne);
        pair_update(P.w, T.w, np, nt, ne);
        if (k < 8) {   // k is unroll-constant: static register bank select
            aeP += np & M; aoP += (np >> 3) & M;
            aeT += nt & M; aoT += (nt >> 3) & M;
            aeE += ne & M; aoE += (ne >> 3) & M;
        } else {
            beP += np & M; boP += (np >> 3) & M;
            beT += nt & M; boT += (nt >> 3) & M;
            beE += ne & M; boE += (ne >> 3) & M;
        }
    }

    // Widen 6-bit fields -> u16-packed per-class counts (class 2j | class 2j+1<<16).
    #pragma unroll
    for (int j = 0; j < 10; ++j) {
        const int sh = 6 * j;
        u32 e, o;
        e = (u32)((aeP >> sh) & 63) + (u32)((beP >> sh) & 63);
        o = (u32)((aoP >> sh) & 63) + (u32)((boP >> sh) & 63);
        sdata[tid * 31 + j] = e | (o << 16);
        e = (u32)((aeT >> sh) & 63) + (u32)((beT >> sh) & 63);
        o = (u32)((aoT >> sh) & 63) + (u32)((boT >> sh) & 63);
        sdata[tid * 31 + 10 + j] = e | (o << 16);
        e = (u32)((aeE >> sh) & 63) + (u32)((beE >> sh) & 63);
        o = (u32)((aoE >> sh) & 63) + (u32)((boE >> sh) & 63);
        sdata[tid * 31 + 20 + j] = e | (o << 16);
    }
    __syncthreads();

    // Block reduce: 8 partials x 30 packed columns (block sums <= 16384, u16-safe).
    u32 part = 0;
    if (tid < 240) {
        const int sub = tid / 30;
        const int j   = tid % 30;
        const int r0  = sub * 32;
        #pragma unroll
        for (int r = 0; r < 32; ++r) part += sdata[(r0 + r) * 31 + j];
    }
    __syncthreads();
    if (tid < 240) sdata[tid] = part;      // rows fully consumed; safe reuse
    __syncthreads();
    if (tid < 30) {
        u32 s = 0;
        #pragma unroll
        for (int q = 0; q < 8; ++q) s += sdata[q * 30 + tid];
        const int hist = tid / 10;
        const int jj   = tid % 10;
        atomicAdd(&gcounts[hist * NC + 2 * jj],     s & 0xFFFFu);
        atomicAdd(&gcounts[hist * NC + 2 * jj + 1], s >> 16);
    }
}

// Generic fallback (any n4): round-4 joint-histogram kernel.
__global__ __launch_bounds__(THREADS) void dice_joint(
    const int* __restrict__ pred, const int* __restrict__ tgt,
    u32* __restrict__ gcounts, long long n4)
{
    __shared__ u32 h[4 * NC * NC];
    const int tid = threadIdx.x;
    for (int k = tid; k < 4 * NC * NC; k += THREADS) h[k] = 0u;
    __syncthreads();
    u32* hw = &h[(tid >> 6) * NC * NC];
    const int4* p4 = (const int4*)pred;
    const int4* t4 = (const int4*)tgt;
    const long long stride = (long long)2048 * THREADS;
    for (long long i = (long long)blockIdx.x * THREADS + tid; i < n4; i += stride) {
        int4 P = p4[i];
        int4 T = t4[i];
        atomicAdd(&hw[P.x * NC + T.x], 1u);
        atomicAdd(&hw[P.y * NC + T.y], 1u);
        atomicAdd(&hw[P.z * NC + T.z], 1u);
        atomicAdd(&hw[P.w * NC + T.w], 1u);
    }
    __syncthreads();
    for (int k = tid; k < NC * NC; k += THREADS)
        h[k] = h[k] + h[NC*NC + k] + h[2*NC*NC + k] + h[3*NC*NC + k];
    __syncthreads();
    if (tid < 3 * (NC - 1)) {
        const int which = tid / (NC - 1);
        const int c     = tid % (NC - 1) + 1;
        u32 s = 0;
        if (which == 0)      { for (int t = 0; t < NC; ++t) s += h[c * NC + t]; }
        else if (which == 1) { for (int p = 0; p < NC; ++p) s += h[p * NC + c]; }
        else                 { s = h[c * NC + c]; }
        atomicAdd(&gcounts[which * NC + c], s);
    }
}

__global__ void dice_final(const u32* __restrict__ gcounts,
                           float* __restrict__ out)
{
    const int c = threadIdx.x;
    float contrib = 0.0f;
    if (c >= 1 && c < NC) {
        float tp = (float)gcounts[2 * NC + c];
        float pc = (float)gcounts[c];
        float tc = (float)gcounts[NC + c];
        contrib = 2.0f * tp / (pc + tc + EPSF);
    }
    #pragma unroll
    for (int d = 32; d >= 1; d >>= 1) contrib += __shfl_down(contrib, d, 64);
    if (c == 0) out[0] = contrib * (1.0f / 19.0f);
}

extern "C" void kernel_launch(void* const* d_in, const int* in_sizes, int n_in,
                              void* d_out, int out_size, void* d_ws, size_t ws_size,
                              hipStream_t stream) {
    const int* pred = (const int*)d_in[0];
    const int* tgt  = (const int*)d_in[1];
    u32* gcounts = (u32*)d_ws;

    hipMemsetAsync(d_ws, 0, 3 * NC * sizeof(u32), stream);

    const int n  = in_sizes[0];        // 16,777,216
    const int n4 = n >> 2;             // 4,194,304 == BLOCKS*THREADS*GRAN

    if (n4 <= BLOCKS * THREADS * GRAN) {
        dice_slice<<<BLOCKS, THREADS, 0, stream>>>(pred, tgt, gcounts, n4);
    } else {
        dice_joint<<<2048, THREADS, 0, stream>>>(pred, tgt, gcounts, (long long)n4);
    }
    dice_final<<<1, 64, 0, stream>>>(gcounts, (float*)d_out);
}